// Round 2
// baseline (287.967 us; speedup 1.0000x reference)
//
#include <hip/hip_runtime.h>

typedef unsigned int u32;
typedef float f32x4 __attribute__((ext_vector_type(4)));

#define BB 8
#define SS 2048
#define KK 16
#define RR 16
#define DIN 2048
#define DOUT 2048

// ---------------------------------------------------------------------------
// Kernel 1: mix the banks (all fp32).
//   Am[b][r][i] = sum_k alpha[b][k] * A_bank[k][r][i]
//   Bm[b][o][r] = sum_k alpha[b][k] * B_bank[k][o][r]
// Unchanged (banks are L2-resident, ~5 us).
// ---------------------------------------------------------------------------
__global__ void __launch_bounds__(256) mix_kernel(
    const float* __restrict__ alpha,
    const float* __restrict__ A_bank,
    const float* __restrict__ B_bank,
    float* __restrict__ Am,
    float* __restrict__ Bm)
{
    int t = blockIdx.x * 256 + threadIdx.x;
    const int half = BB * RR * DIN;  // 262144
    if (t < half) {
        // t = (b*RR + r)*DIN + i   (i fastest -> coalesced)
        int i = t & (DIN - 1);
        int r = (t >> 11) & (RR - 1);
        int b = t >> 15;
        float acc = 0.f;
#pragma unroll
        for (int k = 0; k < KK; ++k)
            acc += alpha[b * KK + k] * A_bank[(k * RR + r) * DIN + i];
        Am[t] = acc;
    } else {
        int u = t - half;
        // u = (b*DOUT + o)*RR + r  (r fastest -> coalesced)
        int r = u & (RR - 1);
        int o = (u >> 4) & (DOUT - 1);
        int b = u >> 15;
        float acc = 0.f;
#pragma unroll
        for (int k = 0; k < KK; ++k)
            acc += alpha[b * KK + k] * B_bank[(k * DOUT + o) * RR + r];
        Bm[u] = acc;
    }
}

// ---------------------------------------------------------------------------
// Kernel 2 (FUSED z + delta): one block owns (b, 8 s-rows).
//
// ROUND-2 CHANGE (AGPR-shunt fix): round-1's wave owned 4 rows x 16 r ->
// a[64] accumulators + ~20 in-flight loads ~= 150-170 live regs at the
// (256,3) cap of ~170 -> allocator shunted a[] into AGPRs (rocprof showed
// arch VGPR_Count=64, no scratch) and every FMA paid accvgpr moves.
// Now: wave owns 2 rows x 16 r -> a[32]; live set ~120, well under cap.
// h still read exactly once device-wide (rows not duplicated across waves);
// Am L1/L2 traffic doubles to ~1 GB (~27 us L1 occupancy, overlaps the
// 20 us HBM h-stream). Block covers 8 rows -> grid (SS/8, B) = (256, 8) =
// 2048 blocks, ~3 resident generations: late blocks' read phase overlaps
// early blocks' write phase (1024-block grid was fully resident = lockstep).
//
// Reduction: payload 32, halving tree d=16..1 within 32-lane halves
// (31 shfl), then one cross-half shfl_xor(32). Lane l (l<32) ends with
// z value index (l&31) = j*16 + r for rows sw+j.
//
// Phase 2: unchanged structure (verified), s-loop over 8 rows.
// ---------------------------------------------------------------------------
__global__ void __launch_bounds__(256, 3) fused_kernel(
    const float* __restrict__ h,
    const float* __restrict__ Am,
    const float* __restrict__ Bm,
    float* __restrict__ out)
{
    __shared__ float zt[8 * 16];    // z tile: zt[s_local*16 + r]

    int b = blockIdx.y;
    int wid = threadIdx.x >> 6;
    int lane = threadIdx.x & 63;
    int s0 = blockIdx.x * 8;              // tile's first s row
    int sw = s0 + wid * 2;                // this wave's first s row

    const float* hb = h + (size_t)b * SS * DIN + (size_t)sw * DIN;
    const float* Ab = Am + (size_t)b * RR * DIN;

    float a[32];
#pragma unroll
    for (int v = 0; v < 32; ++v) a[v] = 0.f;

#pragma unroll 1
    for (int t = 0; t < 8; ++t) {
        int i0 = t * 256 + lane * 4;
        f32x4 hv0 = __builtin_nontemporal_load((const f32x4*)(hb + i0));
        f32x4 hv1 = __builtin_nontemporal_load((const f32x4*)(hb + DIN + i0));
#pragma unroll
        for (int r = 0; r < 16; ++r) {
            f32x4 av = *(const f32x4*)(Ab + r * DIN + i0);
            a[r]      += hv0.x * av.x + hv0.y * av.y + hv0.z * av.z + hv0.w * av.w;
            a[16 + r] += hv1.x * av.x + hv1.y * av.y + hv1.z * av.z + hv1.w * av.w;
        }
    }

    // Halving tree on 32 values within each 32-lane half (31 shfl),
    // then one cross-half combine. Lane l ends with value (l&31).
#pragma unroll
    for (int off = 16; off >= 1; off >>= 1) {
        bool up = (lane & off) != 0;
#pragma unroll
        for (int v = 0; v < off; ++v) {
            float send = up ? a[v] : a[v + off];
            float keep = up ? a[v + off] : a[v];
            a[v] = keep + __shfl_xor(send, off, 64);
        }
    }
    a[0] += __shfl_xor(a[0], 32, 64);
    // value (l&31) = j*16 + r -> zt[(wid*2 + j)*16 + r] = zt[wid*32 + (l&31)]
    if (lane < 32) zt[wid * 32 + lane] = a[0];
    __syncthreads();

    // ------------------- Phase 2: delta tile from LDS z ---------------------
    float* op = out + ((size_t)b * SS + s0) * DOUT;

#pragma unroll 1
    for (int oc = 0; oc < 2; ++oc) {
        int o0 = oc * 1024 + threadIdx.x * 4;
        const float* wp = Bm + ((size_t)b * DOUT + o0) * RR;  // 64 contiguous
        float w[4][16];
#pragma unroll
        for (int j = 0; j < 4; ++j) {
#pragma unroll
            for (int q = 0; q < 4; ++q) {
                f32x4 p = *(const f32x4*)(wp + j * RR + q * 4);
                w[j][q * 4 + 0] = p.x; w[j][q * 4 + 1] = p.y;
                w[j][q * 4 + 2] = p.z; w[j][q * 4 + 3] = p.w;
            }
        }
#pragma unroll 4
        for (int s = 0; s < 8; ++s) {
            // wave-uniform LDS reads -> broadcast, no bank conflicts
            float zz[16];
#pragma unroll
            for (int q = 0; q < 4; ++q) {
                f32x4 zv = *(const f32x4*)(zt + s * 16 + q * 4);
                zz[q * 4 + 0] = zv.x; zz[q * 4 + 1] = zv.y;
                zz[q * 4 + 2] = zv.z; zz[q * 4 + 3] = zv.w;
            }
            float rj[4];
#pragma unroll
            for (int j = 0; j < 4; ++j) {
                float acc = 0.f;
#pragma unroll
                for (int r = 0; r < 16; ++r) acc += w[j][r] * zz[r];
                rj[j] = acc;
            }
            f32x4 res;
            res.x = rj[0]; res.y = rj[1]; res.z = rj[2]; res.w = rj[3];
            __builtin_nontemporal_store(res, (f32x4*)(op + (size_t)s * DOUT + o0));
        }
    }
}

// ---------------------------------------------------------------------------
extern "C" void kernel_launch(void* const* d_in, const int* in_sizes, int n_in,
                              void* d_out, int out_size, void* d_ws, size_t ws_size,
                              hipStream_t stream)
{
    const float* h      = (const float*)d_in[0];   // [B][S][DIN]   fp32
    const float* alpha  = (const float*)d_in[1];   // [B][K]        fp32
    const float* A_bank = (const float*)d_in[2];   // [K][R][DIN]   fp32
    const float* B_bank = (const float*)d_in[3];   // [K][DOUT][R]  fp32
    float* out = (float*)d_out;                    // [B][S][DOUT]  fp32

    // workspace layout (4 MiB total): z not materialized.
    float* Am = (float*)d_ws;                      // [B][R][DIN]  fp32, 2 MiB
    float* Bm = Am + BB * RR * DIN;                // [B][DOUT][R] fp32, 2 MiB

    mix_kernel<<<2048, 256, 0, stream>>>(alpha, A_bank, B_bank, Am, Bm);
    fused_kernel<<<dim3(256, 8), 256, 0, stream>>>(h, Am, Bm, out);
}